// Round 10
// baseline (279.834 us; speedup 1.0000x reference)
//
#include <hip/hip_runtime.h>

// Problem constants
#define N_NODES 25000
#define N_EDGES 200000
// MUL=16, NUM_RADIAL=8, HIDDEN=64, WNUMEL=1024
// PATH_ALPHA=1/sqrt(32), INV_SQRT3=1/sqrt(3), scales folded into B-fragments.

constexpr int ET = 32;      // edges per tile
constexpr int NT = 5;       // tiles per block
constexpr int NBLK = 1250;  // 1250*5*32 = 200000 edges exactly
constexpr int OUTSZ = N_NODES * 64;   // 1,600,000

typedef __attribute__((ext_vector_type(8))) _Float16 half8;  // 8 f16 (4 VGPR)
typedef __attribute__((ext_vector_type(4))) float float4v;   // 4 fp32

__device__ __forceinline__ half8 h8s(half8 a, _Float16 c) { return a * c; }  // v_pk_mul_f16 x4

// ---------------- sc-only kernel (fallback path; round-7 verified) ----------------
__global__ __launch_bounds__(256) void sc_kernel(const float* __restrict__ x,
                                                 const float* __restrict__ L0,
                                                 const float* __restrict__ L1,
                                                 float* __restrict__ out) {
    __shared__ float l0[256], l1[256];
    __shared__ float xs[4][68];
    const int t = threadIdx.x;
    l0[t] = L0[t];
    l1[t] = L1[t];
    const int g = t >> 6, j = t & 63;
    const int n = blockIdx.x * 4 + g;
    xs[g][j] = x[n * 64 + j];
    __syncthreads();
    float s = 0.f;
    if (j < 16) {
        #pragma unroll
        for (int u = 0; u < 16; ++u) s = fmaf(xs[g][u], l0[u * 16 + j], s);
    } else {
        const int q = j - 16, v = q / 3, k = q - 3 * v;
        #pragma unroll
        for (int u = 0; u < 16; ++u) s = fmaf(xs[g][16 + 3 * u + k], l1[u * 16 + v], s);
    }
    out[n * 64 + j] = 0.25f * s;   // 1/sqrt(MUL)
}

// ---------------- reduce kernel: out = sum(replicas) + sc ----------------
__global__ __launch_bounds__(256) void reduce_kernel(const float* __restrict__ ws,
                                                     int rep,
                                                     const float* __restrict__ x,
                                                     const float* __restrict__ L0,
                                                     const float* __restrict__ L1,
                                                     float* __restrict__ out) {
    __shared__ float l0[256], l1[256];
    __shared__ float xs[4][68];
    const int t = threadIdx.x;
    l0[t] = L0[t];
    l1[t] = L1[t];
    const int g = t >> 6, j = t & 63;
    const int n = blockIdx.x * 4 + g;          // 6250 blocks x 4 nodes
    xs[g][j] = x[n * 64 + j];
    __syncthreads();
    float s = 0.f;
    if (j < 16) {
        #pragma unroll
        for (int u = 0; u < 16; ++u) s = fmaf(xs[g][u], l0[u * 16 + j], s);
    } else {
        const int q = j - 16, v = q / 3, k = q - 3 * v;
        #pragma unroll
        for (int u = 0; u < 16; ++u) s = fmaf(xs[g][16 + 3 * u + k], l1[u * 16 + v], s);
    }
    const int idx = n * 64 + j;
    float acc = 0.25f * s;
    for (int r = 0; r < rep; ++r) acc += ws[r * OUTSZ + idx];   // coalesced
    out[idx] = acc;
}

// ---------------- edge kernel (round-9 verified core; scatter target = replica) ----------------
// 512 threads, 8 waves. Wave w: prog = w>>1, uh = w&1 (u in [uh*8, uh*8+8)).
// Per u, A fragment (h rows mt*16+qm, f16) scaled by coef[e][u] feeds MFMA:
//   C[e][v] = sum_u coef[e][u] * sum_c h[e][c]*W2[c][u*16+v]*scale
// Coef planes: 0: xj0*sh0 | 1: b1 | 2: xj0 | 3+k: xj1[.,k]*sh0
// Scatter: atomicAdd into obase + (blockIdx & rep_mask)*OUTSZ  (rep_mask=0 -> out directly)
__global__ __launch_bounds__(512, 4) void edge_kernel(
    const float* __restrict__ x, const float* __restrict__ edge_attr,
    const float* __restrict__ edge_length, const int* __restrict__ edge_src,
    const int* __restrict__ edge_dst, const float* __restrict__ W1,
    const float* __restrict__ W2, float* __restrict__ obase, int rep_mask) {

    const int t = threadIdx.x;
    const int w = t >> 6;             // wave id 0..7
    const int prog = w >> 1;          // which 16x16-block family of w2
    const int uh = w & 1;             // u-half
    const int qm = t & 15;            // MFMA m/n index
    const int quad = (t >> 4) & 3;    // lane quad within wave

    float* const orep = obase + (size_t)(blockIdx.x & rep_mask) * OUTSZ;

    __shared__ __attribute__((aligned(16))) float lds_h[ET * 72];    // fp32 h, stride 72
    __shared__ __attribute__((aligned(16))) float lds_xj[ET * 68];   // gathered x[src], stride 68
    __shared__ __attribute__((aligned(16))) float lds_cf[6 * ET * 17];  // coef planes [pl][e*17+u]
    __shared__ __attribute__((aligned(16))) float lds_xch[12 * ET * 17];// term exchange [pl][e*17+v]
    __shared__ __attribute__((aligned(16))) float lds_w1t[64 * 8];   // W1^T [c][r]
    __shared__ __attribute__((aligned(16))) float lds_sh[ET * 4];
    __shared__ __attribute__((aligned(16))) float lds_len[ET];
    __shared__ __attribute__((aligned(16))) int   lds_dst[ET];

    constexpr int PL = ET * 17;       // plane stride (544)

    // ---- persistent B fragments: W2 block `prog`, u-half `uh`, pre-scaled f16 ----
    // B-frag layout (16x16x32): lane holds B[k = kf*32 + quad*8 + j][n = qm]
    half8 bfr[8][2];
    {
        float scale = 0.0220970869f;                  // (1/sqrt(64)) * (1/sqrt(32))
        if (prog == 1) scale *= 0.5773502692f;        // INV_SQRT3 folded
        const int kr = quad * 8;
        #pragma unroll
        for (int up = 0; up < 8; ++up) {
            const int col = prog * 256 + (uh * 8 + up) * 16 + qm;
            #pragma unroll
            for (int kf = 0; kf < 2; ++kf) {
                half8 f;
                #pragma unroll
                for (int j = 0; j < 8; ++j) {
                    const int k = kf * 32 + kr + j;
                    f[j] = (_Float16)(W2[k * 1024 + col] * scale);
                }
                bfr[up][kf] = f;
            }
        }
    }
    // W1 -> LDS transposed [c][r]
    {
        const int r = t >> 6, c = t & 63;
        lds_w1t[c * 8 + r] = W1[t];
    }

    for (int tl = 0; tl < NT; ++tl) {
        const int e0 = (blockIdx.x * NT + tl) * ET;
        __syncthreads();   // orders prev-tile combine reads before re-staging

        // ---- phase 1: meta + xj gather ----
        if (t < ET) {
            lds_dst[t] = edge_dst[e0 + t];
            lds_len[t] = edge_length[e0 + t];
            const float4v ea = *(const float4v*)(edge_attr + 4 * (e0 + t));
            lds_sh[t * 4 + 0] = ea[0]; lds_sh[t * 4 + 1] = ea[1];
            lds_sh[t * 4 + 2] = ea[2]; lds_sh[t * 4 + 3] = ea[3];
        }
        {
            const int e_loc = t >> 4;                 // 32 edges x 16 threads
            const int src = edge_src[e0 + e_loc];
            const int c4 = (t & 15) * 4;
            *(float4v*)(&lds_xj[e_loc * 68 + c4]) = *(const float4v*)(x + src * 64 + c4);
        }
        __syncthreads();

        // ---- phase 2: coef planes + h (all 512 threads: e = t&31, u = t>>5) ----
        {
            const int e = t & 31, u = t >> 5;
            const float sh0 = lds_sh[e * 4];
            const float s1x = lds_sh[e * 4 + 1];
            const float s1y = lds_sh[e * 4 + 2];
            const float s1z = lds_sh[e * 4 + 3];
            const float xj0v = lds_xj[e * 68 + u];
            const float x0 = lds_xj[e * 68 + 16 + 3 * u];
            const float x1 = lds_xj[e * 68 + 17 + 3 * u];
            const float x2 = lds_xj[e * 68 + 18 + 3 * u];
            lds_cf[0 * PL + e * 17 + u] = xj0v * sh0;
            lds_cf[1 * PL + e * 17 + u] = fmaf(x0, s1x, fmaf(x1, s1y, x2 * s1z));
            lds_cf[2 * PL + e * 17 + u] = xj0v;
            lds_cf[3 * PL + e * 17 + u] = x0 * sh0;
            lds_cf[4 * PL + e * 17 + u] = x1 * sh0;
            lds_cf[5 * PL + e * 17 + u] = x2 * sh0;
            // h = silu(radial @ W1 / sqrt(8)) for (e, c0..c0+3)
            const int c0 = u * 4;
            const float len = lds_len[e];
            float rad[8];
            #pragma unroll
            for (int r = 0; r < 8; ++r) {
                const float d = len - 0.7142857143f * (float)r;
                rad[r] = __expf(-0.5f * d * d);
            }
            float4v hv;
            #pragma unroll
            for (int i = 0; i < 4; ++i) {
                const float4v wA = *(const float4v*)(&lds_w1t[(c0 + i) * 8]);
                const float4v wB = *(const float4v*)(&lds_w1t[(c0 + i) * 8 + 4]);
                float s = rad[0] * wA[0] + rad[1] * wA[1] + rad[2] * wA[2] + rad[3] * wA[3]
                        + rad[4] * wB[0] + rad[5] * wB[1] + rad[6] * wB[2] + rad[7] * wB[3];
                s *= 0.3535533906f;
                hv[i] = s / (1.f + __expf(-s));
            }
            *(float4v*)(&lds_h[e * 72 + c0]) = hv;
        }
        __syncthreads();

        // ---- phase 3: A fragments for both m-tiles (f16, no lo-split) ----
        half8 ah0[2], ah1[2];
        #pragma unroll
        for (int mt = 0; mt < 2; ++mt) {
            const float* hrow = &lds_h[(mt * 16 + qm) * 72];
            const float4v fa = *(const float4v*)(hrow + quad * 8);
            const float4v fb = *(const float4v*)(hrow + quad * 8 + 4);
            const float4v fc = *(const float4v*)(hrow + 32 + quad * 8);
            const float4v fd = *(const float4v*)(hrow + 32 + quad * 8 + 4);
            #pragma unroll
            for (int j = 0; j < 4; ++j) {
                ah0[mt][j]     = (_Float16)fa[j];
                ah0[mt][4 + j] = (_Float16)fb[j];
                ah1[mt][j]     = (_Float16)fc[j];
                ah1[mt][4 + j] = (_Float16)fd[j];
            }
        }

        // ---- MFMA with per-u coef-scaled A; C = final per-edge term ----
        // C layout per m-tile: row e = mt*16 + quad*4 + r, col v = qm
        if (prog < 3) {
            float4v acc[2];
            acc[0] = (float4v){0.f, 0.f, 0.f, 0.f};
            acc[1] = (float4v){0.f, 0.f, 0.f, 0.f};
            #pragma unroll
            for (int up = 0; up < 8; ++up) {
                const int u = uh * 8 + up;
                #pragma unroll
                for (int mt = 0; mt < 2; ++mt) {
                    const _Float16 c = (_Float16)lds_cf[prog * PL + (mt * 16 + qm) * 17 + u];
                    acc[mt] = __builtin_amdgcn_mfma_f32_16x16x32_f16(h8s(ah0[mt], c), bfr[up][0], acc[mt], 0, 0, 0);
                    acc[mt] = __builtin_amdgcn_mfma_f32_16x16x32_f16(h8s(ah1[mt], c), bfr[up][1], acc[mt], 0, 0, 0);
                }
            }
            float* xb = &lds_xch[w * PL];
            #pragma unroll
            for (int mt = 0; mt < 2; ++mt)
                #pragma unroll
                for (int r = 0; r < 4; ++r)
                    xb[(mt * 16 + quad * 4 + r) * 17 + qm] = acc[mt][r];
        } else {
            float4v a3[2][3];
            #pragma unroll
            for (int mt = 0; mt < 2; ++mt)
                #pragma unroll
                for (int k = 0; k < 3; ++k) a3[mt][k] = (float4v){0.f, 0.f, 0.f, 0.f};
            #pragma unroll
            for (int up = 0; up < 8; ++up) {
                const int u = uh * 8 + up;
                #pragma unroll
                for (int mt = 0; mt < 2; ++mt) {
                    #pragma unroll
                    for (int k = 0; k < 3; ++k) {
                        const _Float16 c = (_Float16)lds_cf[(3 + k) * PL + (mt * 16 + qm) * 17 + u];
                        a3[mt][k] = __builtin_amdgcn_mfma_f32_16x16x32_f16(h8s(ah0[mt], c), bfr[up][0], a3[mt][k], 0, 0, 0);
                        a3[mt][k] = __builtin_amdgcn_mfma_f32_16x16x32_f16(h8s(ah1[mt], c), bfr[up][1], a3[mt][k], 0, 0, 0);
                    }
                }
            }
            #pragma unroll
            for (int k = 0; k < 3; ++k) {
                float* xb = &lds_xch[(6 + uh * 3 + k) * PL];
                #pragma unroll
                for (int mt = 0; mt < 2; ++mt)
                    #pragma unroll
                    for (int r = 0; r < 4; ++r)
                        xb[(mt * 16 + quad * 4 + r) * 17 + qm] = a3[mt][k][r];
            }
        }
        __syncthreads();

        // ---- combine: 4 output elems per thread, ONE atomic each (to replica) ----
        #pragma unroll
        for (int i = 0; i < 4; ++i) {
            const int idx = t + 512 * i;          // 2048 = 32 edges x 64 elems
            const int e = idx >> 6, j = idx & 63;
            float val;
            if (j < 16) {
                val = (lds_xch[0 * PL + e * 17 + j] + lds_xch[1 * PL + e * 17 + j])
                    + (lds_xch[2 * PL + e * 17 + j] + lds_xch[3 * PL + e * 17 + j]);
            } else {
                const int q = j - 16, v = q / 3, k = q - 3 * v;
                const float s2 = lds_xch[4 * PL + e * 17 + v] + lds_xch[5 * PL + e * 17 + v];
                const float s3 = lds_xch[(6 + k) * PL + e * 17 + v]
                               + lds_xch[(9 + k) * PL + e * 17 + v];
                val = fmaf(s2, lds_sh[e * 4 + 1 + k], s3);
            }
            atomicAdd(orep + lds_dst[e] * 64 + j, val);
        }
        // next-iteration top barrier orders these LDS reads before re-staging
    }
}

extern "C" void kernel_launch(void* const* d_in, const int* in_sizes, int n_in,
                              void* d_out, int out_size, void* d_ws, size_t ws_size,
                              hipStream_t stream) {
    const float* x           = (const float*)d_in[0];
    const float* edge_attr   = (const float*)d_in[1];
    const float* edge_length = (const float*)d_in[2];
    const int*   edge_src    = (const int*)d_in[3];
    const int*   edge_dst    = (const int*)d_in[4];
    const float* W1          = (const float*)d_in[5];
    const float* W2          = (const float*)d_in[6];
    const float* L0          = (const float*)d_in[7];
    const float* L1          = (const float*)d_in[8];
    float* out = (float*)d_out;

    // choose replica count by available workspace
    int rep = 0;
    for (int r = 8; r >= 2; r >>= 1) {
        if (ws_size >= (size_t)r * OUTSZ * sizeof(float)) { rep = r; break; }
    }

    if (rep > 0) {
        float* ws = (float*)d_ws;
        hipMemsetAsync(ws, 0, (size_t)rep * OUTSZ * sizeof(float), stream);
        edge_kernel<<<NBLK, 512, 0, stream>>>(
            x, edge_attr, edge_length, edge_src, edge_dst, W1, W2, ws, rep - 1);
        reduce_kernel<<<N_NODES / 4, 256, 0, stream>>>(ws, rep, x, L0, L1, out);
    } else {
        // fallback: exact round-9 path
        sc_kernel<<<N_NODES / 4, 256, 0, stream>>>(x, L0, L1, out);
        edge_kernel<<<NBLK, 512, 0, stream>>>(
            x, edge_attr, edge_length, edge_src, edge_dst, W1, W2, out, 0);
    }
}